// Round 1
// baseline (593.668 us; speedup 1.0000x reference)
//
#include <hip/hip_runtime.h>
#include <hip/hip_bf16.h>
#include <cstdint>
#include <cstddef>

#define T_SEQ 4096
#define C_DIM 2048
#define NH    16
#define NKV   4
#define HD    128
#define NQKV  3072   // 2048 q + 512 k + 512 v
#define KVB   32

using bf16x8 = __attribute__((ext_vector_type(8))) __bf16;
using u16x8  = __attribute__((ext_vector_type(8))) unsigned short;
using f32x4  = __attribute__((ext_vector_type(4))) float;
typedef unsigned short ushort_t;

__device__ __forceinline__ float b2f(ushort_t u) {
  union { unsigned int i; float f; } x; x.i = ((unsigned int)u) << 16; return x.f;
}
__device__ __forceinline__ ushort_t f2b(float f) {
  union { float f; unsigned int i; } x; x.f = f;
  unsigned int r = x.i + 0x7FFFu + ((x.i >> 16) & 1u);   // RNE
  return (ushort_t)(r >> 16);
}

// async global->LDS, 16B per lane. LDS dest = wave-uniform base + lane*16.
__device__ __forceinline__ void gload16(const ushort_t* g, ushort_t* l) {
  __builtin_amdgcn_global_load_lds(
      (const __attribute__((address_space(1))) unsigned int*)g,
      (__attribute__((address_space(3))) unsigned int*)l, 16, 0, 0);
}

__device__ __forceinline__ f32x4 mfma_bf16(u16x8 a, u16x8 b, f32x4 c) {
  return __builtin_amdgcn_mfma_f32_16x16x32_bf16(
      __builtin_bit_cast(bf16x8, a), __builtin_bit_cast(bf16x8, b), c, 0, 0, 0);
}

// ---------------- fp32 -> bf16 convert (x) ----------------
__global__ void k_cvt(const float* __restrict__ in, ushort_t* __restrict__ out, int n) {
  int i = (blockIdx.x * 256 + threadIdx.x) * 8;
  if (i >= n) return;
  float4 a = *(const float4*)(in + i);
  float4 b = *(const float4*)(in + i + 4);
  ushort_t o[8] = { f2b(a.x), f2b(a.y), f2b(a.z), f2b(a.w),
                    f2b(b.x), f2b(b.y), f2b(b.z), f2b(b.w) };
  *(uint4*)(out + i) = *(const uint4*)o;
}

// ---------------- W [K][N] fp32 -> WT [N][K] bf16 ----------------
__global__ void k_transpose_cvt(const float* __restrict__ W, ushort_t* __restrict__ WT,
                                int K, int N) {
  __shared__ float tile[32][33];
  int n0 = blockIdx.x * 32, k0 = blockIdx.y * 32;
  int tx = threadIdx.x, ty = threadIdx.y;   // 32 x 8
  #pragma unroll
  for (int i = 0; i < 32; i += 8)
    tile[ty + i][tx] = W[(size_t)(k0 + ty + i) * N + (n0 + tx)];
  __syncthreads();
  #pragma unroll
  for (int i = 0; i < 32; i += 8)
    WT[(size_t)(n0 + ty + i) * K + (k0 + tx)] = f2b(tile[tx][ty + i]);
}

// ---------------- RoPE tables: cos/sin [T][64] fp32 ----------------
__global__ void k_rope_tables(float* __restrict__ cosT, float* __restrict__ sinT) {
  int idx = blockIdx.x * 256 + threadIdx.x;     // t*64 + d
  int t = idx >> 6, d = idx & 63;
  float inv = powf(10000.0f, -(float)d * (1.0f / 64.0f));
  float freq = (float)t * inv;
  cosT[idx] = cosf(freq);
  sinT[idx] = sinf(freq);
}

// ---------------- m97-structure GEMM: C = A (MxK) * Bt^T (Bt is [N][K]) ----------------
template<int OUT_BF16>
__global__ __launch_bounds__(256) void k_gemm_bt(const ushort_t* __restrict__ A,
                                                 const ushort_t* __restrict__ Bt,
                                                 void* __restrict__ Cout,
                                                 int M, int N, int K) {
  __shared__ ushort_t As[128 * 32];
  __shared__ ushort_t Bs[128 * 32];
  const int w = threadIdx.x >> 6, l = threadIdx.x & 63;
  const int wm = w >> 1, wn = w & 1;
  const int lr = l & 15, lg = l >> 4;
  const int m0 = blockIdx.x * 128, n0 = blockIdx.y * 128;

  // staging: call i covers rows i*64 + w*16 + (l>>2), cols (l&3)*8 .. +8
  const int srow = w * 16 + (l >> 2);
  const int scol = (l & 3) * 8;
  const ushort_t* gA = A  + (size_t)(m0 + srow) * K + scol;
  const ushort_t* gB = Bt + (size_t)(n0 + srow) * K + scol;
  ushort_t* lA = As + w * 512;   // wave-uniform LDS base (bytes: w*1024)
  ushort_t* lB = Bs + w * 512;

  f32x4 acc[4][4];
  #pragma unroll
  for (int i = 0; i < 4; i++)
    #pragma unroll
    for (int j = 0; j < 4; j++) acc[i][j] = f32x4{0.f, 0.f, 0.f, 0.f};

  for (int kt = 0; kt < K; kt += 32) {
    gload16(gA + kt,                    lA);
    gload16(gA + kt + (size_t)64 * K,   lA + 2048);
    gload16(gB + kt,                    lB);
    gload16(gB + kt + (size_t)64 * K,   lB + 2048);
    __syncthreads();   // compiler drains vmcnt before s_barrier

    u16x8 af[4], bfm[4];
    #pragma unroll
    for (int mi = 0; mi < 4; mi++)
      af[mi] = *(const u16x8*)&As[(wm * 64 + mi * 16 + lr) * 32 + lg * 8];
    #pragma unroll
    for (int ni = 0; ni < 4; ni++)
      bfm[ni] = *(const u16x8*)&Bs[(wn * 64 + ni * 16 + lr) * 32 + lg * 8];
    #pragma unroll
    for (int mi = 0; mi < 4; mi++)
      #pragma unroll
      for (int ni = 0; ni < 4; ni++)
        acc[mi][ni] = mfma_bf16(af[mi], bfm[ni], acc[mi][ni]);
    __syncthreads();
  }

  #pragma unroll
  for (int mi = 0; mi < 4; mi++) {
    #pragma unroll
    for (int ni = 0; ni < 4; ni++) {
      const int row = m0 + wm * 64 + mi * 16 + lg * 4;
      const int col = n0 + wn * 64 + ni * 16 + lr;
      #pragma unroll
      for (int r = 0; r < 4; r++) {
        if (OUT_BF16)
          ((ushort_t*)Cout)[(size_t)(row + r) * N + col] = f2b(acc[mi][ni][r]);
        else
          ((float*)Cout)[(size_t)(row + r) * N + col] = acc[mi][ni][r];
      }
    }
  }
}

// ---------------- RMSNorm + RoPE + scatter to attention layouts ----------------
// slot 0..15: q head -> Qr[h][t][d] (pre-scaled by 1/sqrt(D))
// slot 16..19: k head -> Kr[g][t][d];  slot 20..23: v copy -> Vr[g][t][d]
__global__ void k_rms_rope(const ushort_t* __restrict__ QKV,
                           const float* __restrict__ cosT, const float* __restrict__ sinT,
                           ushort_t* __restrict__ Qr, ushort_t* __restrict__ Kr,
                           ushort_t* __restrict__ Vr) {
  const int slot = blockIdx.x;                 // 0..23
  const int w = threadIdx.x >> 6, l = threadIdx.x & 63;
  const int t = blockIdx.y * 4 + w;
  const ushort_t* src = QKV + (size_t)t * NQKV + slot * HD;   // slot*128 hits q/k/v regions
  if (slot >= 20) {
    ushort_t* dst = Vr + ((size_t)(slot - 20) * T_SEQ + t) * HD;
    dst[l] = src[l]; dst[l + 64] = src[l + 64];
    return;
  }
  float x1 = b2f(src[l]), x2 = b2f(src[l + 64]);
  float ss = x1 * x1 + x2 * x2;
  #pragma unroll
  for (int m = 1; m < 64; m <<= 1) ss += __shfl_xor(ss, m);
  float rms = rsqrtf(ss * (1.0f / 128.0f) + 1e-6f);
  float c = cosT[t * 64 + l], s = sinT[t * 64 + l];
  float y1 = (x1 * c - x2 * s) * rms;
  float y2 = (x2 * c + x1 * s) * rms;
  ushort_t* dst;
  if (slot < 16) {
    y1 *= 0.08838834764831845f;  y2 *= 0.08838834764831845f;   // 1/sqrt(128)
    dst = Qr + ((size_t)slot * T_SEQ + t) * HD;
  } else {
    dst = Kr + ((size_t)(slot - 16) * T_SEQ + t) * HD;
  }
  dst[l] = f2b(y1); dst[l + 64] = f2b(y2);
}

// ---------------- causal GQA flash attention ----------------
// grid = 64 q-tiles x 16 heads; block 256 = 4 waves, wave owns 16 q-rows.
__global__ __launch_bounds__(256) void k_attn(const ushort_t* __restrict__ Qr,
                                              const ushort_t* __restrict__ Kr,
                                              const ushort_t* __restrict__ Vr,
                                              ushort_t* __restrict__ O) {
  __shared__ ushort_t Ks[KVB][136];     // +8 pad -> 2-way-only conflicts on b128 reads
  __shared__ ushort_t Vt[HD][40];       // V transposed, +8 pad
  __shared__ ushort_t Ps[4][16][40];    // per-wave P tile

  const int bid = blockIdx.x;
  const int h = bid & 15;
  const int qt = 63 - (bid >> 4);       // heaviest q-tiles dispatch first
  const int g = h >> 2;                 // kv head
  const int w = threadIdx.x >> 6, l = threadIdx.x & 63;
  const int lr = l & 15, lg = l >> 4;
  const int q0 = qt * 64;
  const int qw = q0 + w * 16;

  // Q fragments (pre-scaled): a_frag[j] = Q[lr][kk*32 + lg*8 + j]
  const ushort_t* Qp = Qr + (((size_t)h * T_SEQ + qw) + lr) * HD + lg * 8;
  u16x8 qf[4];
  #pragma unroll
  for (int kk = 0; kk < 4; kk++) qf[kk] = *(const u16x8*)(Qp + kk * 32);

  const ushort_t* Kh = Kr + (size_t)g * T_SEQ * HD;
  const ushort_t* Vh = Vr + (size_t)g * T_SEQ * HD;

  f32x4 oacc[8];
  #pragma unroll
  for (int n = 0; n < 8; n++) oacc[n] = f32x4{0.f, 0.f, 0.f, 0.f};
  float m_run[4] = {-1e30f, -1e30f, -1e30f, -1e30f};
  float l_run[4] = {0.f, 0.f, 0.f, 0.f};

  const int srow = threadIdx.x >> 3;          // 0..31
  const int scol = (threadIdx.x & 7) * 16;    // 0..112

  const int ktiles = (q0 + 64) / KVB;
  for (int kt = 0; kt < ktiles; kt++) {
    const int kv0 = kt * KVB;
    {   // stage K rows + V transposed
      const ushort_t* kp = Kh + (size_t)(kv0 + srow) * HD + scol;
      const ushort_t* vp = Vh + (size_t)(kv0 + srow) * HD + scol;
      u16x8 kk0 = *(const u16x8*)kp;
      u16x8 kk1 = *(const u16x8*)(kp + 8);
      *(u16x8*)&Ks[srow][scol]     = kk0;
      *(u16x8*)&Ks[srow][scol + 8] = kk1;
      u16x8 vv0 = *(const u16x8*)vp;
      u16x8 vv1 = *(const u16x8*)(vp + 8);
      #pragma unroll
      for (int j = 0; j < 8; j++) {
        Vt[scol + j][srow]     = vv0[j];
        Vt[scol + 8 + j][srow] = vv1[j];
      }
    }
    __syncthreads();

    if (kv0 <= qw + 15) {     // wave-uniform
      f32x4 s0 = {0.f,0.f,0.f,0.f}, s1 = {0.f,0.f,0.f,0.f};
      #pragma unroll
      for (int kk = 0; kk < 4; kk++) {
        u16x8 b0 = *(const u16x8*)&Ks[lr][kk * 32 + lg * 8];
        u16x8 b1 = *(const u16x8*)&Ks[16 + lr][kk * 32 + lg * 8];
        s0 = mfma_bf16(qf[kk], b0, s0);
        s1 = mfma_bf16(qf[kk], b1, s1);
      }
      #pragma unroll
      for (int r = 0; r < 4; r++) {
        const int qrow = qw + lg * 4 + r;
        float v0 = (kv0 + lr      <= qrow) ? s0[r] : -1e30f;
        float v1 = (kv0 + 16 + lr <= qrow) ? s1[r] : -1e30f;
        float mx = fmaxf(v0, v1);
        mx = fmaxf(mx, __shfl_xor(mx, 1));
        mx = fmaxf(mx, __shfl_xor(mx, 2));
        mx = fmaxf(mx, __shfl_xor(mx, 4));
        mx = fmaxf(mx, __shfl_xor(mx, 8));
        const float mnew = fmaxf(m_run[r], mx);
        const float alpha = __expf(m_run[r] - mnew);
        const float p0 = __expf(v0 - mnew);
        const float p1 = __expf(v1 - mnew);
        m_run[r] = mnew;
        float ps = p0 + p1;
        ps += __shfl_xor(ps, 1); ps += __shfl_xor(ps, 2);
        ps += __shfl_xor(ps, 4); ps += __shfl_xor(ps, 8);
        l_run[r] = l_run[r] * alpha + ps;
        Ps[w][lg * 4 + r][lr]      = f2b(p0);
        Ps[w][lg * 4 + r][16 + lr] = f2b(p1);
        #pragma unroll
        for (int n = 0; n < 8; n++) oacc[n][r] *= alpha;
      }
      // PV: A = P[16][32] (from own wave's LDS), B = V^T
      u16x8 pa = *(const u16x8*)&Ps[w][lr][lg * 8];
      #pragma unroll
      for (int n = 0; n < 8; n++) {
        u16x8 vb = *(const u16x8*)&Vt[n * 16 + lr][lg * 8];
        oacc[n] = mfma_bf16(pa, vb, oacc[n]);
      }
    }
    __syncthreads();
  }

  #pragma unroll
  for (int r = 0; r < 4; r++) {
    const float inv = 1.0f / l_run[r];
    const int qrow = qw + lg * 4 + r;
    #pragma unroll
    for (int n = 0; n < 8; n++)
      O[(size_t)qrow * (NH * HD) + h * HD + n * 16 + lr] = f2b(oacc[n][r] * inv);
  }
}

extern "C" void kernel_launch(void* const* d_in, const int* in_sizes, int n_in,
                              void* d_out, int out_size, void* d_ws, size_t ws_size,
                              hipStream_t stream) {
  (void)in_sizes; (void)n_in; (void)out_size; (void)ws_size;
  const float* x  = (const float*)d_in[0];
  const float* Wq = (const float*)d_in[1];
  const float* Wk = (const float*)d_in[2];
  const float* Wv = (const float*)d_in[3];
  const float* Wo = (const float*)d_in[4];
  float* out = (float*)d_out;

  char* ws = (char*)d_ws;
  size_t off = 0;
  auto alloc = [&](size_t bytes) -> void* {
    void* p = ws + off;
    off = (off + bytes + 255) & ~(size_t)255;
    return p;
  };

  ushort_t* xb    = (ushort_t*)alloc((size_t)T_SEQ * C_DIM * 2);
  ushort_t* WqkvT = (ushort_t*)alloc((size_t)NQKV * C_DIM * 2);
  ushort_t* WoT   = (ushort_t*)alloc((size_t)C_DIM * C_DIM * 2);
  ushort_t* QKV   = (ushort_t*)alloc((size_t)T_SEQ * NQKV * 2);
  ushort_t* Qbuf  = (ushort_t*)alloc((size_t)NH * T_SEQ * HD * 2);
  ushort_t* Kbuf  = (ushort_t*)alloc((size_t)NKV * T_SEQ * HD * 2);
  ushort_t* Vbuf  = (ushort_t*)alloc((size_t)NKV * T_SEQ * HD * 2);
  ushort_t* Obuf  = (ushort_t*)alloc((size_t)T_SEQ * NH * HD * 2);
  float*    cosT  = (float*)alloc((size_t)T_SEQ * 64 * 4);
  float*    sinT  = (float*)alloc((size_t)T_SEQ * 64 * 4);

  k_cvt<<<4096, 256, 0, stream>>>(x, xb, T_SEQ * C_DIM);

  k_transpose_cvt<<<dim3(64, 64), dim3(32, 8), 0, stream>>>(Wq, WqkvT, C_DIM, 2048);
  k_transpose_cvt<<<dim3(16, 64), dim3(32, 8), 0, stream>>>(Wk, WqkvT + (size_t)2048 * C_DIM, C_DIM, 512);
  k_transpose_cvt<<<dim3(16, 64), dim3(32, 8), 0, stream>>>(Wv, WqkvT + (size_t)2560 * C_DIM, C_DIM, 512);
  k_transpose_cvt<<<dim3(64, 64), dim3(32, 8), 0, stream>>>(Wo, WoT, C_DIM, C_DIM);

  k_rope_tables<<<1024, 256, 0, stream>>>(cosT, sinT);

  // QKV = xb @ WqkvT^T : M=4096, N=3072, K=2048
  k_gemm_bt<1><<<dim3(32, 24), 256, 0, stream>>>(xb, WqkvT, QKV, T_SEQ, NQKV, C_DIM);

  k_rms_rope<<<dim3(24, 1024), 256, 0, stream>>>(QKV, cosT, sinT, Qbuf, Kbuf, Vbuf);

  k_attn<<<1024, 256, 0, stream>>>(Qbuf, Kbuf, Vbuf, Obuf);

  // out = Obuf @ WoT^T : M=4096, N=2048, K=2048 (fp32 out)
  k_gemm_bt<0><<<dim3(32, 16), 256, 0, stream>>>(Obuf, WoT, out, T_SEQ, C_DIM, C_DIM);
}

// Round 5
// 406.692 us; speedup vs baseline: 1.4597x; 1.4597x over previous
//
#include <hip/hip_runtime.h>
#include <hip/hip_bf16.h>
#include <cstdint>
#include <cstddef>

#define T_SEQ 4096
#define C_DIM 2048
#define NH    16
#define NKV   4
#define HD    128
#define NQKV  3072   // 2048 q + 512 k + 512 v

using bf16x8 = __attribute__((ext_vector_type(8))) __bf16;
using u16x8  = __attribute__((ext_vector_type(8))) unsigned short;
using f32x4  = __attribute__((ext_vector_type(4))) float;
using f32x16 = __attribute__((ext_vector_type(16))) float;
using u32x4  = __attribute__((ext_vector_type(4))) unsigned int;
using u32x8  = __attribute__((ext_vector_type(8))) unsigned int;
typedef unsigned short ushort_t;

__device__ __forceinline__ float b2f(ushort_t u) {
  union { unsigned int i; float f; } x; x.i = ((unsigned int)u) << 16; return x.f;
}
__device__ __forceinline__ ushort_t f2b(float f) {
  union { float f; unsigned int i; } x; x.f = f;
  unsigned int r = x.i + 0x7FFFu + ((x.i >> 16) & 1u);   // RNE
  return (ushort_t)(r >> 16);
}
__device__ __forceinline__ unsigned int packbf2(float lo, float hi) {
  return ((unsigned int)f2b(hi) << 16) | (unsigned int)f2b(lo);
}

// async global->LDS, 16B per lane. LDS dest = wave-uniform base + lane*16.
__device__ __forceinline__ void gload16(const ushort_t* g, ushort_t* l) {
  __builtin_amdgcn_global_load_lds(
      (const __attribute__((address_space(1))) unsigned int*)g,
      (__attribute__((address_space(3))) unsigned int*)l, 16, 0, 0);
}

__device__ __forceinline__ f32x4 mfma_bf16(u16x8 a, u16x8 b, f32x4 c) {
  return __builtin_amdgcn_mfma_f32_16x16x32_bf16(
      __builtin_bit_cast(bf16x8, a), __builtin_bit_cast(bf16x8, b), c, 0, 0, 0);
}
__device__ __forceinline__ f32x16 mfma32(u16x8 a, u16x8 b, f32x16 c) {
  return __builtin_amdgcn_mfma_f32_32x32x16_bf16(
      __builtin_bit_cast(bf16x8, a), __builtin_bit_cast(bf16x8, b), c, 0, 0, 0);
}

// ---------------- fp32 -> bf16 convert (x) ----------------
__global__ void k_cvt(const float* __restrict__ in, ushort_t* __restrict__ out, int n) {
  int i = (blockIdx.x * 256 + threadIdx.x) * 8;
  if (i >= n) return;
  float4 a = *(const float4*)(in + i);
  float4 b = *(const float4*)(in + i + 4);
  ushort_t o[8] = { f2b(a.x), f2b(a.y), f2b(a.z), f2b(a.w),
                    f2b(b.x), f2b(b.y), f2b(b.z), f2b(b.w) };
  *(uint4*)(out + i) = *(const uint4*)o;
}

// ---------------- W [K][N] fp32 -> WT [N][K] bf16 ----------------
__global__ void k_transpose_cvt(const float* __restrict__ W, ushort_t* __restrict__ WT,
                                int K, int N) {
  __shared__ float tile[32][33];
  int n0 = blockIdx.x * 32, k0 = blockIdx.y * 32;
  int tx = threadIdx.x, ty = threadIdx.y;   // 32 x 8
  #pragma unroll
  for (int i = 0; i < 32; i += 8)
    tile[ty + i][tx] = W[(size_t)(k0 + ty + i) * N + (n0 + tx)];
  __syncthreads();
  #pragma unroll
  for (int i = 0; i < 32; i += 8)
    WT[(size_t)(n0 + ty + i) * K + (k0 + tx)] = f2b(tile[tx][ty + i]);
}

// ---------------- RoPE tables: cos/sin [T][64] fp32 ----------------
__global__ void k_rope_tables(float* __restrict__ cosT, float* __restrict__ sinT) {
  int idx = blockIdx.x * 256 + threadIdx.x;     // t*64 + d
  int t = idx >> 6, d = idx & 63;
  float inv = powf(10000.0f, -(float)d * (1.0f / 64.0f));
  float freq = (float)t * inv;
  cosT[idx] = cosf(freq);
  sinT[idx] = sinf(freq);
}

// ---------------- m97-structure GEMM: C = A (MxK) * Bt^T (Bt is [N][K]) ----------------
template<int OUT_BF16>
__global__ __launch_bounds__(256) void k_gemm_bt(const ushort_t* __restrict__ A,
                                                 const ushort_t* __restrict__ Bt,
                                                 void* __restrict__ Cout,
                                                 int M, int N, int K) {
  __shared__ ushort_t As[128 * 32];
  __shared__ ushort_t Bs[128 * 32];
  const int w = threadIdx.x >> 6, l = threadIdx.x & 63;
  const int wm = w >> 1, wn = w & 1;
  const int lr = l & 15, lg = l >> 4;
  const int m0 = blockIdx.x * 128, n0 = blockIdx.y * 128;

  const int srow = w * 16 + (l >> 2);
  const int scol = (l & 3) * 8;
  const ushort_t* gA = A  + (size_t)(m0 + srow) * K + scol;
  const ushort_t* gB = Bt + (size_t)(n0 + srow) * K + scol;
  ushort_t* lA = As + w * 512;
  ushort_t* lB = Bs + w * 512;

  f32x4 acc[4][4];
  #pragma unroll
  for (int i = 0; i < 4; i++)
    #pragma unroll
    for (int j = 0; j < 4; j++) acc[i][j] = f32x4{0.f, 0.f, 0.f, 0.f};

  for (int kt = 0; kt < K; kt += 32) {
    gload16(gA + kt,                    lA);
    gload16(gA + kt + (size_t)64 * K,   lA + 2048);
    gload16(gB + kt,                    lB);
    gload16(gB + kt + (size_t)64 * K,   lB + 2048);
    __syncthreads();

    u16x8 af[4], bfm[4];
    #pragma unroll
    for (int mi = 0; mi < 4; mi++)
      af[mi] = *(const u16x8*)&As[(wm * 64 + mi * 16 + lr) * 32 + lg * 8];
    #pragma unroll
    for (int ni = 0; ni < 4; ni++)
      bfm[ni] = *(const u16x8*)&Bs[(wn * 64 + ni * 16 + lr) * 32 + lg * 8];
    #pragma unroll
    for (int mi = 0; mi < 4; mi++)
      #pragma unroll
      for (int ni = 0; ni < 4; ni++)
        acc[mi][ni] = mfma_bf16(af[mi], bfm[ni], acc[mi][ni]);
    __syncthreads();
  }

  #pragma unroll
  for (int mi = 0; mi < 4; mi++) {
    #pragma unroll
    for (int ni = 0; ni < 4; ni++) {
      const int row = m0 + wm * 64 + mi * 16 + lg * 4;
      const int col = n0 + wn * 64 + ni * 16 + lr;
      #pragma unroll
      for (int r = 0; r < 4; r++) {
        if (OUT_BF16)
          ((ushort_t*)Cout)[(size_t)(row + r) * N + col] = f2b(acc[mi][ni][r]);
        else
          ((float*)Cout)[(size_t)(row + r) * N + col] = acc[mi][ni][r];
      }
    }
  }
}

// ---------------- RMSNorm + RoPE + scatter (q/k only) ----------------
// slot 0..15: q head -> Qr[h][t][d] (pre-scaled); slot 16..19: k -> Kr[g][t][d]
__global__ void k_rms_rope(const ushort_t* __restrict__ QKV,
                           const float* __restrict__ cosT, const float* __restrict__ sinT,
                           ushort_t* __restrict__ Qr, ushort_t* __restrict__ Kr) {
  const int slot = blockIdx.x;                 // 0..19
  const int w = threadIdx.x >> 6, l = threadIdx.x & 63;
  const int t = blockIdx.y * 4 + w;
  const ushort_t* src = QKV + (size_t)t * NQKV + slot * HD;
  float x1 = b2f(src[l]), x2 = b2f(src[l + 64]);
  float ss = x1 * x1 + x2 * x2;
  #pragma unroll
  for (int m = 1; m < 64; m <<= 1) ss += __shfl_xor(ss, m);
  float rms = rsqrtf(ss * (1.0f / 128.0f) + 1e-6f);
  float c = cosT[t * 64 + l], s = sinT[t * 64 + l];
  float y1 = (x1 * c - x2 * s) * rms;
  float y2 = (x2 * c + x1 * s) * rms;
  ushort_t* dst;
  if (slot < 16) {
    y1 *= 0.08838834764831845f;  y2 *= 0.08838834764831845f;   // 1/sqrt(128)
    dst = Qr + ((size_t)slot * T_SEQ + t) * HD;
  } else {
    dst = Kr + ((size_t)(slot - 16) * T_SEQ + t) * HD;
  }
  dst[l] = f2b(y1); dst[l + 64] = f2b(y2);
}

// ---------------- V transpose: Vt[c][t] = QKV[t][2560 + c], c = g*128 + d ----------------
__global__ void k_vt(const ushort_t* __restrict__ QKV, ushort_t* __restrict__ Vt) {
  __shared__ ushort_t tile[64][65];
  const int t0 = blockIdx.x * 64, c0 = blockIdx.y * 64;
  const int tx = threadIdx.x & 63, ty = threadIdx.x >> 6;   // 64 x 4
  #pragma unroll
  for (int i = ty; i < 64; i += 4)
    tile[i][tx] = QKV[(size_t)(t0 + i) * NQKV + 2560 + c0 + tx];
  __syncthreads();
  #pragma unroll
  for (int i = ty; i < 64; i += 4)
    Vt[(size_t)(c0 + i) * T_SEQ + t0 + tx] = tile[tx][i];
}

// ---------------- causal GQA flash attention v3 ----------------
// 4 waves x 32 q-rows = 128 q/block; KVB=64; swapped QK^T (mfma32(K,Q));
// K LDS [64][128] and V^T LDS [128][64], both XOR-block-swizzled via
// pre-swizzled global_load_lds source (rule #21 pattern). No tr_read.
#define PV_STEP(KS, WW, XX)                                                    \
  {                                                                            \
    constexpr int S4 = (KS & 1) * 4;                                           \
    unsigned int a0 = hi ? XX[S4 + 2] : WW[S4];                                \
    unsigned int a1 = hi ? XX[S4 + 3] : WW[S4 + 1];                            \
    unsigned int a2 = hi ? WW[S4 + 2] : XX[S4];                                \
    unsigned int a3 = hi ? WW[S4 + 3] : XX[S4 + 1];                            \
    u32x4 paw = {a0, a1, a2, a3};                                              \
    u16x8 pa = __builtin_bit_cast(u16x8, paw);                                 \
    const int cb = ((KS * 2 + hi) ^ (m & 7)) * 8;                              \
    u16x8 vb0 = *(const u16x8*)&Vs[(m)      * 64 + cb];                        \
    u16x8 vb1 = *(const u16x8*)&Vs[(32 + m) * 64 + cb];                        \
    u16x8 vb2 = *(const u16x8*)&Vs[(64 + m) * 64 + cb];                        \
    u16x8 vb3 = *(const u16x8*)&Vs[(96 + m) * 64 + cb];                        \
    oacc0 = mfma32(pa, vb0, oacc0);                                            \
    oacc1 = mfma32(pa, vb1, oacc1);                                            \
    oacc2 = mfma32(pa, vb2, oacc2);                                            \
    oacc3 = mfma32(pa, vb3, oacc3);                                            \
  }

__global__ __launch_bounds__(256, 2) void k_attn(const ushort_t* __restrict__ Qr,
                                                 const ushort_t* __restrict__ Kr,
                                                 const ushort_t* __restrict__ Vt,
                                                 ushort_t* __restrict__ O) {
  __shared__ ushort_t KsU[64 * 128];   // [kv row][d], block-col ^= (row&7)
  __shared__ ushort_t Vs[128 * 64];    // [d][kv], block-col ^= (d&7)
  __shared__ float aSm[4][32];

  const int bid = blockIdx.x;
  const int h = bid & 15;
  const int qtile = 31 - (bid >> 4);            // heavy q-tiles first
  const int g = h >> 2;
  const int tid = threadIdx.x;
  const int w = tid >> 6, l = tid & 63;
  const int m = l & 31, hi = l >> 5;
  const int qb = qtile * 128;
  const int qw = qb + w * 32;                   // wave's first q row
  const int q_abs = qw + m;

  const ushort_t* Kh = Kr + (size_t)g * T_SEQ * HD;
  const ushort_t* Vh = Vt + (size_t)g * HD * T_SEQ;

  // Q fragments: qf[dblk][j] = Q[qw + m][dblk*16 + hi*8 + j]  (pre-scaled)
  const ushort_t* Qp = Qr + ((size_t)h * T_SEQ + qw + m) * HD + hi * 8;
  u16x8 qf[8];
  #pragma unroll
  for (int dblk = 0; dblk < 8; dblk++) qf[dblk] = *(const u16x8*)(Qp + dblk * 16);

  // staging address precompute (pre-swizzled sources)
  const int kt_row = tid >> 4;                                  // 0..15
  const int kt_col = (((tid & 15) ^ (kt_row & 7)) * 8);         // ushort
  const int vt_row = tid >> 3;                                  // 0..31
  const int vt_col = (((tid & 7) ^ (vt_row & 7)) * 8);          // ushort

  f32x16 oacc0 = {}, oacc1 = {}, oacc2 = {}, oacc3 = {};
  float m_run = -1e30f, l_run = 0.f;

  const int kv_end = qb + 128;
  for (int kv0 = 0; kv0 < kv_end; kv0 += 64) {
    #pragma unroll
    for (int c = 0; c < 4; c++)
      gload16(Kh + (size_t)(kv0 + c * 16 + kt_row) * HD + kt_col,
              KsU + c * 2048 + w * 512);
    #pragma unroll
    for (int c = 0; c < 4; c++)
      gload16(Vh + (size_t)(c * 32 + vt_row) * T_SEQ + kv0 + vt_col,
              Vs + c * 2048 + w * 512);
    __syncthreads();

    if (kv0 <= qw + 31) {
      // ---- QK^T (swapped): S^T[k][q], two 32-k sub-tiles ----
      f32x16 sA = {}, sB = {};
      __builtin_amdgcn_s_setprio(1);
      #pragma unroll
      for (int dblk = 0; dblk < 8; dblk++) {
        const int e = (dblk * 16 + hi * 8) ^ ((m & 7) * 8);
        u16x8 ka = *(const u16x8*)&KsU[m * 128 + e];
        u16x8 kb = *(const u16x8*)&KsU[(32 + m) * 128 + e];
        sA = mfma32(ka, qf[dblk], sA);
        sB = mfma32(kb, qf[dblk], sB);
      }
      __builtin_amdgcn_s_setprio(0);

      if (kv0 + 63 > qw) {          // diagonal tile: causal mask
        #pragma unroll
        for (int r = 0; r < 16; r++) {
          const int klocal = (r & 3) + ((r >> 2) << 3) + (hi << 2);
          sA[r] = (kv0 + klocal <= q_abs) ? sA[r] : -1e30f;
          sB[r] = (kv0 + 32 + klocal <= q_abs) ? sB[r] : -1e30f;
        }
      }

      // ---- online softmax (in-register row reduce; lane owns q=qw+m) ----
      float pmax = -1e30f;
      #pragma unroll
      for (int r = 0; r < 16; r++) pmax = fmaxf(pmax, fmaxf(sA[r], sB[r]));
      pmax = fmaxf(pmax, __shfl_xor(pmax, 32));

      if (__any(pmax > m_run + 8.0f)) {       // rescale (rare after tile 0)
        const float mnew = fmaxf(m_run, pmax);
        const float alpha = __expf(m_run - mnew);
        m_run = mnew;
        l_run *= alpha;
        if (l < 32) aSm[w][l] = alpha;
        f32x16 av;
        #pragma unroll
        for (int r = 0; r < 16; r++)
          av[r] = aSm[w][(r & 3) + ((r >> 2) << 3) + (hi << 2)];
        oacc0 *= av; oacc1 *= av; oacc2 *= av; oacc3 *= av;
      }

      float ps = 0.f;
      #pragma unroll
      for (int r = 0; r < 16; r++) {
        sA[r] = __expf(sA[r] - m_run);
        sB[r] = __expf(sB[r] - m_run);
        ps += sA[r] + sB[r];
      }
      ps += __shfl_xor(ps, 32);
      l_run += ps;

      // ---- pack P to bf16 words + cross-half exchange ----
      u32x8 wA, wB, xA, xB;
      #pragma unroll
      for (int i = 0; i < 8; i++) {
        wA[i] = packbf2(sA[2 * i], sA[2 * i + 1]);
        wB[i] = packbf2(sB[2 * i], sB[2 * i + 1]);
      }
      #pragma unroll
      for (int i = 0; i < 8; i++) {
        xA[i] = (unsigned int)__shfl_xor((int)wA[i], 32);
        xB[i] = (unsigned int)__shfl_xor((int)wB[i], 32);
      }

      // ---- PV: O[q][d] += P[q][k] V[k][d] ----
      __builtin_amdgcn_s_setprio(1);
      PV_STEP(0, wA, xA)
      PV_STEP(1, wA, xA)
      PV_STEP(2, wB, xB)
      PV_STEP(3, wB, xB)
      __builtin_amdgcn_s_setprio(0);
    }
    __syncthreads();
  }

  // ---- epilogue: normalize + store ----
  if (l < 32) aSm[w][l] = 1.0f / l_run;
  f32x16 inv;
  #pragma unroll
  for (int r = 0; r < 16; r++)
    inv[r] = aSm[w][(r & 3) + ((r >> 2) << 3) + (hi << 2)];
  oacc0 *= inv; oacc1 *= inv; oacc2 *= inv; oacc3 *= inv;

  #pragma unroll
  for (int r = 0; r < 16; r++) {
    const int row = qw + (r & 3) + ((r >> 2) << 3) + (hi << 2);
    ushort_t* op = O + (size_t)row * (NH * HD) + h * HD + m;
    op[0]  = f2b(oacc0[r]);
    op[32] = f2b(oacc1[r]);
    op[64] = f2b(oacc2[r]);
    op[96] = f2b(oacc3[r]);
  }
}

extern "C" void kernel_launch(void* const* d_in, const int* in_sizes, int n_in,
                              void* d_out, int out_size, void* d_ws, size_t ws_size,
                              hipStream_t stream) {
  (void)in_sizes; (void)n_in; (void)out_size; (void)ws_size;
  const float* x  = (const float*)d_in[0];
  const float* Wq = (const float*)d_in[1];
  const float* Wk = (const float*)d_in[2];
  const float* Wv = (const float*)d_in[3];
  const float* Wo = (const float*)d_in[4];
  float* out = (float*)d_out;

  char* ws = (char*)d_ws;
  size_t off = 0;
  auto alloc = [&](size_t bytes) -> void* {
    void* p = ws + off;
    off = (off + bytes + 255) & ~(size_t)255;
    return p;
  };

  ushort_t* xb    = (ushort_t*)alloc((size_t)T_SEQ * C_DIM * 2);
  ushort_t* WqkvT = (ushort_t*)alloc((size_t)NQKV * C_DIM * 2);
  ushort_t* WoT   = (ushort_t*)alloc((size_t)C_DIM * C_DIM * 2);
  ushort_t* QKV   = (ushort_t*)alloc((size_t)T_SEQ * NQKV * 2);
  ushort_t* Qbuf  = (ushort_t*)alloc((size_t)NH * T_SEQ * HD * 2);
  ushort_t* Kbuf  = (ushort_t*)alloc((size_t)NKV * T_SEQ * HD * 2);
  ushort_t* Vbuf  = (ushort_t*)alloc((size_t)NKV * T_SEQ * HD * 2);   // transposed [g][d][t]
  ushort_t* Obuf  = (ushort_t*)alloc((size_t)T_SEQ * NH * HD * 2);
  float*    cosT  = (float*)alloc((size_t)T_SEQ * 64 * 4);
  float*    sinT  = (float*)alloc((size_t)T_SEQ * 64 * 4);

  k_cvt<<<4096, 256, 0, stream>>>(x, xb, T_SEQ * C_DIM);

  k_transpose_cvt<<<dim3(64, 64), dim3(32, 8), 0, stream>>>(Wq, WqkvT, C_DIM, 2048);
  k_transpose_cvt<<<dim3(16, 64), dim3(32, 8), 0, stream>>>(Wk, WqkvT + (size_t)2048 * C_DIM, C_DIM, 512);
  k_transpose_cvt<<<dim3(16, 64), dim3(32, 8), 0, stream>>>(Wv, WqkvT + (size_t)2560 * C_DIM, C_DIM, 512);
  k_transpose_cvt<<<dim3(64, 64), dim3(32, 8), 0, stream>>>(Wo, WoT, C_DIM, C_DIM);

  k_rope_tables<<<1024, 256, 0, stream>>>(cosT, sinT);

  // QKV = xb @ WqkvT^T : M=4096, N=3072, K=2048
  k_gemm_bt<1><<<dim3(32, 24), 256, 0, stream>>>(xb, WqkvT, QKV, T_SEQ, NQKV, C_DIM);

  k_rms_rope<<<dim3(20, 1024), 256, 0, stream>>>(QKV, cosT, sinT, Qbuf, Kbuf);
  k_vt<<<dim3(64, 8), 256, 0, stream>>>(QKV, Vbuf);

  k_attn<<<512, 256, 0, stream>>>(Qbuf, Kbuf, Vbuf, Obuf);

  // out = Obuf @ WoT^T : M=4096, N=2048, K=2048 (fp32 out)
  k_gemm_bt<0><<<dim3(32, 16), 256, 0, stream>>>(Obuf, WoT, out, T_SEQ, C_DIM, C_DIM);
}